// Round 15
// baseline (131.975 us; speedup 1.0000x reference)
//
#include <hip/hip_runtime.h>

#define HH 160
#define WW 160
#define DD 16
#define NG 8192
#define VOXEL 0.4f

// tiles: 20 x 20 x 4 (each 8x8x4 voxels) = 1600 tiles
#define TTX 20
#define TTY 20
#define TTZ 4
#define NTILES (TTX * TTY * TTZ)
#define CAP 128        // survivors per tile: lambda ~61, P(>128) ~ 8.6 sigma
#define PSTRIDE (NTILES * CAP)   // float4 stride between SoA planes

// d_ws layout:
//   tileCnt  : NTILES int (6.4 KB)                    @ 0
//   tilePack : 4 planes x NTILES*CAP float4 (13.1 MB) @ 64 KB  (SoA)
// plane0 = (mu.x, mu.y, mu.z, opacity)
// plane1 = (3sx,  3sy,  3sz,  as_float(g))
// plane2 = (ci00, ci01, ci02, ci11)
// plane3 = (ci12, ci22, 0, 0)

__global__ __launch_bounds__(64) void gv_precompute_bin(
    const float* __restrict__ means, const float* __restrict__ opac,
    const float* __restrict__ scales, const float* __restrict__ rots,
    int* __restrict__ tileCnt, float4* __restrict__ tilePack) {
  int g = blockIdx.x * 64 + threadIdx.x;
  if (g >= NG) return;
  float qw = rots[g * 4 + 0], qx = rots[g * 4 + 1];
  float qy = rots[g * 4 + 2], qz = rots[g * 4 + 3];
  float inv = rsqrtf(qw * qw + qx * qx + qy * qy + qz * qz);
  qw *= inv; qx *= inv; qy *= inv; qz *= inv;
  float R[3][3];
  R[0][0] = 1.f - 2.f * (qy * qy + qz * qz);
  R[0][1] = 2.f * (qx * qy - qw * qz);
  R[0][2] = 2.f * (qx * qz + qw * qy);
  R[1][0] = 2.f * (qx * qy + qw * qz);
  R[1][1] = 1.f - 2.f * (qx * qx + qz * qz);
  R[1][2] = 2.f * (qy * qz - qw * qx);
  R[2][0] = 2.f * (qx * qz - qw * qy);
  R[2][1] = 2.f * (qy * qz + qw * qx);
  R[2][2] = 1.f - 2.f * (qx * qx + qy * qy);
  float sx = scales[g * 3 + 0], sy = scales[g * 3 + 1], sz = scales[g * 3 + 2];
  float s2[3] = {sx * sx, sy * sy, sz * sz};
  float is2[3] = {1.f / s2[0], 1.f / s2[1], 1.f / s2[2]};
  float cov00 = 0.f, cov11 = 0.f, cov22 = 0.f;
  float ci00 = 0.f, ci01 = 0.f, ci02 = 0.f, ci11 = 0.f, ci12 = 0.f, ci22 = 0.f;
#pragma unroll
  for (int c = 0; c < 3; c++) {
    cov00 += R[0][c] * R[0][c] * s2[c];
    cov11 += R[1][c] * R[1][c] * s2[c];
    cov22 += R[2][c] * R[2][c] * s2[c];
    ci00 += R[0][c] * R[0][c] * is2[c];
    ci01 += R[0][c] * R[1][c] * is2[c];
    ci02 += R[0][c] * R[2][c] * is2[c];
    ci11 += R[1][c] * R[1][c] * is2[c];
    ci12 += R[1][c] * R[2][c] * is2[c];
    ci22 += R[2][c] * R[2][c] * is2[c];
  }
  float mx = means[g * 3 + 0], my = means[g * 3 + 1], mz = means[g * 3 + 2];
  float bx = 3.f * sqrtf(cov00), by = 3.f * sqrtf(cov11), bz = 3.f * sqrtf(cov22);

  const float eps = 1e-4f;
  int i0 = (int)ceilf((mx - bx + 32.f) * 2.5f - 0.5f - eps);
  int i1 = (int)floorf((mx + bx + 32.f) * 2.5f - 0.5f + eps);
  int j0 = (int)ceilf((my - by + 32.f) * 2.5f - 0.5f - eps);
  int j1 = (int)floorf((my + by + 32.f) * 2.5f - 0.5f + eps);
  int k0 = (int)ceilf((mz - bz + 1.f) * 2.5f - 0.5f - eps);
  int k1 = (int)floorf((mz + bz + 1.f) * 2.5f - 0.5f + eps);
  i0 = max(i0, 0); i1 = min(i1, HH - 1);
  j0 = max(j0, 0); j1 = min(j1, WW - 1);
  k0 = max(k0, 0); k1 = min(k1, DD - 1);
  if (i0 > i1 || j0 > j1 || k0 > k1) return;

  float4 p0 = make_float4(mx, my, mz, opac[g]);
  float4 p1 = make_float4(bx, by, bz, __int_as_float(g));
  float4 p2 = make_float4(ci00, ci01, ci02, ci11);
  float4 p3 = make_float4(ci12, ci22, 0.f, 0.f);

  int ti0 = i0 >> 3, ti1 = i1 >> 3;
  int tj0 = j0 >> 3, tj1 = j1 >> 3;
  int tk0 = k0 >> 2, tk1 = k1 >> 2;
  for (int ti = ti0; ti <= ti1; ti++)
    for (int tj = tj0; tj <= tj1; tj++)
      for (int tk = tk0; tk <= tk1; tk++) {
        int t = (ti * TTY + tj) * TTZ + tk;
        int pos = atomicAdd(&tileCnt[t], 1);
        if (pos < CAP) {
          size_t row = (size_t)t * CAP + pos;
          tilePack[row] = p0;
          tilePack[PSTRIDE + row] = p1;
          tilePack[2 * PSTRIDE + row] = p2;
          tilePack[3 * PSTRIDE + row] = p3;
        }
      }
}

// Voxelize: wave-level cull + survivor-only processing. No LDS.
// Cull: lane m vector-loads gaussian m's SoA record (coalesced, vmcnt) and
// box-tests its bbox against the wave's 2x8x4 voxel-center slab (exact;
// grid step 0.4 < 2*b_min -> slab-interval test == __any(per-voxel in);
// +1e-5 slack makes boundary-ulp flips harmless false-positives).
// Survivors via __ballot; per pair: readlane(index) -> feats s_load (SGPR),
// 13 __shfl pulls of params from cull registers (no memory), ONE lgkmcnt
// wait, then gate+maha+FMA with no divergent branch.
__global__ __launch_bounds__(256) void gv_voxelize(
    const float4* __restrict__ feats, const int* __restrict__ tileCnt,
    const float4* __restrict__ tilePack, float4* __restrict__ out) {
  int tid = threadIdx.x;
  int lane = tid & 63;
  int w = tid >> 6;
  int dk = tid & 3, dj = (tid >> 2) & 7, di = tid >> 5;
  int tk = blockIdx.x, tj = blockIdx.y, ti = blockIdx.z;
  int i = ti * 8 + di, j = tj * 8 + dj, k = tk * 4 + dk;

  float px = (i + 0.5f) * VOXEL - 32.f;
  float py = (j + 0.5f) * VOXEL - 32.f;
  float pz = (k + 0.5f) * VOXEL - 1.f;

  // wave slab voxel-center bounds (uniform; same fp expressions as px/py/pz)
  const float SLK = 1e-5f;
  float cxlo = (ti * 8 + 2 * w + 0.5f) * VOXEL - 32.f;
  float cxhi = (ti * 8 + 2 * w + 1 + 0.5f) * VOXEL - 32.f;
  float cylo = (tj * 8 + 0.5f) * VOXEL - 32.f;
  float cyhi = (tj * 8 + 7 + 0.5f) * VOXEL - 32.f;
  float czlo = (tk * 4 + 0.5f) * VOXEL - 1.f;
  float czhi = (tk * 4 + 3 + 0.5f) * VOXEL - 1.f;

  int t = (ti * TTY + tj) * TTZ + tk;
  int cnt = tileCnt[t];
  cnt = min(cnt, CAP);

  float4 acc[8];
#pragma unroll
  for (int f = 0; f < 8; f++) acc[f] = make_float4(0.f, 0.f, 0.f, 0.f);

#define SURV_BODY(M)                                                          \
  do {                                                                        \
    int _idx = __builtin_amdgcn_readlane(__float_as_int(pk1.w), (M));         \
    const float4* __restrict__ _fp = feats + (size_t)_idx * 8;                \
    float4 F[8];                                                              \
    _Pragma("unroll")                                                         \
    for (int f = 0; f < 8; f++) F[f] = _fp[f];                                \
    float mux = __shfl(pk0.x, (M)), muy = __shfl(pk0.y, (M));                 \
    float muz = __shfl(pk0.z, (M)), op = __shfl(pk0.w, (M));                  \
    float bbx = __shfl(pk1.x, (M)), bby = __shfl(pk1.y, (M));                 \
    float bbz = __shfl(pk1.z, (M));                                           \
    float q00 = __shfl(pk2.x, (M)), q01 = __shfl(pk2.y, (M));                 \
    float q02 = __shfl(pk2.z, (M)), q11 = __shfl(pk2.w, (M));                 \
    float q12 = __shfl(pk3.x, (M)), q22 = __shfl(pk3.y, (M));                 \
    float dx = px - mux, dy = py - muy, dz = pz - muz;                        \
    bool in = (fabsf(dx) <= bbx) & (fabsf(dy) <= bby) & (fabsf(dz) <= bbz);   \
    float maha = q00 * dx * dx + q11 * dy * dy + q22 * dz * dz +              \
                 2.f * (q01 * dx * dy + q02 * dx * dz + q12 * dy * dz);       \
    float wgt = in ? op * __expf(-0.5f * maha) : 0.f;                         \
    _Pragma("unroll")                                                         \
    for (int f = 0; f < 8; f++) {                                             \
      acc[f].x += wgt * F[f].x;                                               \
      acc[f].y += wgt * F[f].y;                                               \
      acc[f].z += wgt * F[f].z;                                               \
      acc[f].w += wgt * F[f].w;                                               \
    }                                                                         \
  } while (0)

  for (int base = 0; base < cnt; base += 64) {
    int m = base + lane;
    int mm = min(m, cnt - 1);           // in-bounds clamp; masked below
    size_t row = (size_t)t * CAP + mm;
    float4 pk0 = tilePack[row];
    float4 pk1 = tilePack[PSTRIDE + row];
    float4 pk2 = tilePack[2 * PSTRIDE + row];
    float4 pk3 = tilePack[3 * PSTRIDE + row];

    bool sv = (m < cnt) &
              (pk0.x >= cxlo - pk1.x - SLK) & (pk0.x <= cxhi + pk1.x + SLK) &
              (pk0.y >= cylo - pk1.y - SLK) & (pk0.y <= cyhi + pk1.y + SLK) &
              (pk0.z >= czlo - pk1.z - SLK) & (pk0.z <= czhi + pk1.z + SLK);
    unsigned long long mask = __ballot(sv);

    while (mask) {
      int m0 = __ffsll(mask) - 1; mask &= mask - 1;
      if (mask) {
        int m1 = __ffsll(mask) - 1; mask &= mask - 1;
        SURV_BODY(m0);
        SURV_BODY(m1);
      } else {
        SURV_BODY(m0);
      }
    }
  }
#undef SURV_BODY

  size_t v = ((size_t)i * WW + j) * DD + k;
  float4* o = out + v * 8;
#pragma unroll
  for (int f = 0; f < 8; f++) o[f] = acc[f];
}

extern "C" void kernel_launch(void* const* d_in, const int* in_sizes, int n_in,
                              void* d_out, int out_size, void* d_ws, size_t ws_size,
                              hipStream_t stream) {
  const float* means  = (const float*)d_in[0];
  const float* opac   = (const float*)d_in[1];
  const float* scales = (const float*)d_in[2];
  const float* rots   = (const float*)d_in[3];
  const float4* feats = (const float4*)d_in[4];

  char* ws = (char*)d_ws;
  int* tileCnt     = (int*)ws;                        // 6.4 KB
  float4* tilePack = (float4*)(ws + 64 * 1024);       // 13.1 MB (4 SoA planes)

  hipMemsetAsync(tileCnt, 0, NTILES * sizeof(int), stream);
  gv_precompute_bin<<<128, 64, 0, stream>>>(means, opac, scales, rots,
                                            tileCnt, tilePack);
  dim3 grid(TTZ, TTY, TTX);
  gv_voxelize<<<grid, 256, 0, stream>>>(feats, tileCnt, tilePack,
                                        (float4*)d_out);
}

// Round 16
// 123.399 us; speedup vs baseline: 1.0695x; 1.0695x over previous
//
#include <hip/hip_runtime.h>

#define HH 160
#define WW 160
#define DD 16
#define NG 8192
#define VOXEL 0.4f

// tiles: 20 x 20 x 4 (each 8x8x4 voxels) = 1600 tiles
#define TTX 20
#define TTY 20
#define TTZ 4
#define NTILES (TTX * TTY * TTZ)
#define CAP 128   // survivors per tile: lambda ~61, P(>128) ~ 8.6 sigma -> safe

// d_ws layout:
//   tileCnt  : NTILES int (6.4 KB)                @ 0
//   tileIdx  : NTILES * CAP int (800 KB)          @ 64 KB
//   tilePack : NTILES * CAP * 4 float4 (13.1 MB)  @ 1 MB
// tilePack record (4 float4 = 64 B), R13 layout:
//   [0] = (mu.x, mu.y, mu.z, opacity)
//   [1] = (3sx,  3sy,  3sz,  as_float(g))   <- gate data, always read
//   [2] = (ci00, ci01, ci02, ci11)          <- read only when __any(pass)
//   [3] = (ci12, ci22, 0, 0)
// tileIdx mirrors the list order; the voxelize loop streams it with
// loop-linear uniform s_loads prefetched one pair ahead, so the feats
// s_load no longer waits on the gate ds_read (chain 520 -> ~400 cyc).

__global__ __launch_bounds__(64) void gv_precompute_bin(
    const float* __restrict__ means, const float* __restrict__ opac,
    const float* __restrict__ scales, const float* __restrict__ rots,
    int* __restrict__ tileCnt, int* __restrict__ tileIdx,
    float4* __restrict__ tilePack) {
  int g = blockIdx.x * 64 + threadIdx.x;
  if (g >= NG) return;
  float qw = rots[g * 4 + 0], qx = rots[g * 4 + 1];
  float qy = rots[g * 4 + 2], qz = rots[g * 4 + 3];
  float inv = rsqrtf(qw * qw + qx * qx + qy * qy + qz * qz);
  qw *= inv; qx *= inv; qy *= inv; qz *= inv;
  float R[3][3];
  R[0][0] = 1.f - 2.f * (qy * qy + qz * qz);
  R[0][1] = 2.f * (qx * qy - qw * qz);
  R[0][2] = 2.f * (qx * qz + qw * qy);
  R[1][0] = 2.f * (qx * qy + qw * qz);
  R[1][1] = 1.f - 2.f * (qx * qx + qz * qz);
  R[1][2] = 2.f * (qy * qz - qw * qx);
  R[2][0] = 2.f * (qx * qz - qw * qy);
  R[2][1] = 2.f * (qy * qz + qw * qx);
  R[2][2] = 1.f - 2.f * (qx * qx + qy * qy);
  float sx = scales[g * 3 + 0], sy = scales[g * 3 + 1], sz = scales[g * 3 + 2];
  float s2[3] = {sx * sx, sy * sy, sz * sz};
  float is2[3] = {1.f / s2[0], 1.f / s2[1], 1.f / s2[2]};
  float cov00 = 0.f, cov11 = 0.f, cov22 = 0.f;
  float ci00 = 0.f, ci01 = 0.f, ci02 = 0.f, ci11 = 0.f, ci12 = 0.f, ci22 = 0.f;
#pragma unroll
  for (int c = 0; c < 3; c++) {
    cov00 += R[0][c] * R[0][c] * s2[c];
    cov11 += R[1][c] * R[1][c] * s2[c];
    cov22 += R[2][c] * R[2][c] * s2[c];
    ci00 += R[0][c] * R[0][c] * is2[c];
    ci01 += R[0][c] * R[1][c] * is2[c];
    ci02 += R[0][c] * R[2][c] * is2[c];
    ci11 += R[1][c] * R[1][c] * is2[c];
    ci12 += R[1][c] * R[2][c] * is2[c];
    ci22 += R[2][c] * R[2][c] * is2[c];
  }
  float mx = means[g * 3 + 0], my = means[g * 3 + 1], mz = means[g * 3 + 2];
  float bx = 3.f * sqrtf(cov00), by = 3.f * sqrtf(cov11), bz = 3.f * sqrtf(cov22);

  const float eps = 1e-4f;
  int i0 = (int)ceilf((mx - bx + 32.f) * 2.5f - 0.5f - eps);
  int i1 = (int)floorf((mx + bx + 32.f) * 2.5f - 0.5f + eps);
  int j0 = (int)ceilf((my - by + 32.f) * 2.5f - 0.5f - eps);
  int j1 = (int)floorf((my + by + 32.f) * 2.5f - 0.5f + eps);
  int k0 = (int)ceilf((mz - bz + 1.f) * 2.5f - 0.5f - eps);
  int k1 = (int)floorf((mz + bz + 1.f) * 2.5f - 0.5f + eps);
  i0 = max(i0, 0); i1 = min(i1, HH - 1);
  j0 = max(j0, 0); j1 = min(j1, WW - 1);
  k0 = max(k0, 0); k1 = min(k1, DD - 1);
  if (i0 > i1 || j0 > j1 || k0 > k1) return;

  float4 p0 = make_float4(mx, my, mz, opac[g]);
  float4 p1 = make_float4(bx, by, bz, __int_as_float(g));
  float4 p2 = make_float4(ci00, ci01, ci02, ci11);
  float4 p3 = make_float4(ci12, ci22, 0.f, 0.f);

  int ti0 = i0 >> 3, ti1 = i1 >> 3;
  int tj0 = j0 >> 3, tj1 = j1 >> 3;
  int tk0 = k0 >> 2, tk1 = k1 >> 2;
  for (int ti = ti0; ti <= ti1; ti++)
    for (int tj = tj0; tj <= tj1; tj++)
      for (int tk = tk0; tk <= tk1; tk++) {
        int t = (ti * TTY + tj) * TTZ + tk;
        int pos = atomicAdd(&tileCnt[t], 1);
        if (pos < CAP) {
          size_t row = (size_t)t * CAP + pos;
          tileIdx[row] = g;
          float4* __restrict__ d = tilePack + row * 4;
          d[0] = p0;  d[1] = p1;  d[2] = p2;  d[3] = p3;
        }
      }
}

// Voxelize: R13 structure (LDS pack staging + gated ci + early uniform
// feats s_load, 4 waves/block) with the first chain link removed: gaussian
// indices stream from tileIdx via loop-linear uniform s_loads prefetched
// one pair ahead (2 SGPRs). The feats s_load for pair n issues at iteration
// start, in PARALLEL with the gate ds_read, instead of after it.
__global__ __launch_bounds__(256) void gv_voxelize(
    const float4* __restrict__ feats, const int* __restrict__ tileCnt,
    const int* __restrict__ tileIdx, const float4* __restrict__ tilePack,
    float4* __restrict__ out) {
  __shared__ float4 s_pack[CAP * 4];   // 8 KB

  int tid = threadIdx.x;
  int dk = tid & 3, dj = (tid >> 2) & 7, di = tid >> 5;
  int tk = blockIdx.x, tj = blockIdx.y, ti = blockIdx.z;
  int i = ti * 8 + di, j = tj * 8 + dj, k = tk * 4 + dk;

  float px = (i + 0.5f) * VOXEL - 32.f;
  float py = (j + 0.5f) * VOXEL - 32.f;
  float pz = (k + 0.5f) * VOXEL - 1.f;

  int t = (ti * TTY + tj) * TTZ + tk;
  int cnt = tileCnt[t];
  cnt = min(cnt, CAP);
  const int* __restrict__ idxArr = tileIdx + (size_t)t * CAP;

  // stage pack records (coalesced, parallel)
  {
    const float4* __restrict__ src = tilePack + (size_t)t * CAP * 4;
    int tot = cnt * 4;
    for (int m = tid; m < tot; m += 256) s_pack[m] = src[m];
  }
  __syncthreads();

  float4 acc[8];
#pragma unroll
  for (int f = 0; f < 8; f++) acc[f] = make_float4(0.f, 0.f, 0.f, 0.f);

  int n = 0;
  int ci0 = 0, ci1 = 0;
  if (cnt >= 2) { ci0 = idxArr[0]; ci1 = idxArr[1]; }
  for (; n + 2 <= cnt; n += 2) {
    int g0 = ci0, g1 = ci1;
    // prefetch next pair's indices (uniform s_load; completes under this
    // iteration's drain, so next iteration's feats load issues immediately)
    if (n + 4 <= cnt) { ci0 = idxArr[n + 2]; ci1 = idxArr[n + 3]; }

    const float4* __restrict__ fp0 = feats + (size_t)g0 * 8;
    const float4* __restrict__ fp1 = feats + (size_t)g1 * 8;
    // feats s_loads issue now, in parallel with the gate ds_reads below
    float4 F0[8], F1[8];
#pragma unroll
    for (int f = 0; f < 8; f++) F0[f] = fp0[f];
#pragma unroll
    for (int f = 0; f < 8; f++) F1[f] = fp1[f];

    float4 a0 = s_pack[n * 4 + 0], b0 = s_pack[n * 4 + 1];
    float4 a1 = s_pack[n * 4 + 4], b1 = s_pack[n * 4 + 5];

    float dx0 = px - a0.x, dy0 = py - a0.y, dz0 = pz - a0.z;
    float dx1 = px - a1.x, dy1 = py - a1.y, dz1 = pz - a1.z;
    bool in0 = (fabsf(dx0) <= b0.x) & (fabsf(dy0) <= b0.y) & (fabsf(dz0) <= b0.z);
    bool in1 = (fabsf(dx1) <= b1.x) & (fabsf(dy1) <= b1.y) & (fabsf(dz1) <= b1.z);

    if (__any(in0)) {
      float4 c0 = s_pack[n * 4 + 2], d0 = s_pack[n * 4 + 3];
      float maha = c0.x * dx0 * dx0 + c0.w * dy0 * dy0 + d0.y * dz0 * dz0 +
                   2.f * (c0.y * dx0 * dy0 + c0.z * dx0 * dz0 + d0.x * dy0 * dz0);
      float wgt = in0 ? a0.w * __expf(-0.5f * maha) : 0.f;
#pragma unroll
      for (int f = 0; f < 8; f++) {
        acc[f].x += wgt * F0[f].x;
        acc[f].y += wgt * F0[f].y;
        acc[f].z += wgt * F0[f].z;
        acc[f].w += wgt * F0[f].w;
      }
    }
    if (__any(in1)) {
      float4 c1 = s_pack[n * 4 + 6], d1 = s_pack[n * 4 + 7];
      float maha = c1.x * dx1 * dx1 + c1.w * dy1 * dy1 + d1.y * dz1 * dz1 +
                   2.f * (c1.y * dx1 * dy1 + c1.z * dx1 * dz1 + d1.x * dy1 * dz1);
      float wgt = in1 ? a1.w * __expf(-0.5f * maha) : 0.f;
#pragma unroll
      for (int f = 0; f < 8; f++) {
        acc[f].x += wgt * F1[f].x;
        acc[f].y += wgt * F1[f].y;
        acc[f].z += wgt * F1[f].z;
        acc[f].w += wgt * F1[f].w;
      }
    }
  }
  if (n < cnt) {
    int gg = idxArr[n];
    const float4* __restrict__ fp = feats + (size_t)gg * 8;
    float4 pa = s_pack[n * 4 + 0], pb = s_pack[n * 4 + 1];
    float dx = px - pa.x, dy = py - pa.y, dz = pz - pa.z;
    bool in = (fabsf(dx) <= pb.x) & (fabsf(dy) <= pb.y) & (fabsf(dz) <= pb.z);
    if (__any(in)) {
      float4 pc = s_pack[n * 4 + 2], pd = s_pack[n * 4 + 3];
      float maha = pc.x * dx * dx + pc.w * dy * dy + pd.y * dz * dz +
                   2.f * (pc.y * dx * dy + pc.z * dx * dz + pd.x * dy * dz);
      float wgt = in ? pa.w * __expf(-0.5f * maha) : 0.f;
#pragma unroll
      for (int f = 0; f < 8; f++) {
        float4 fv = fp[f];
        acc[f].x += wgt * fv.x;
        acc[f].y += wgt * fv.y;
        acc[f].z += wgt * fv.z;
        acc[f].w += wgt * fv.w;
      }
    }
  }

  size_t v = ((size_t)i * WW + j) * DD + k;
  float4* o = out + v * 8;
#pragma unroll
  for (int f = 0; f < 8; f++) o[f] = acc[f];
}

extern "C" void kernel_launch(void* const* d_in, const int* in_sizes, int n_in,
                              void* d_out, int out_size, void* d_ws, size_t ws_size,
                              hipStream_t stream) {
  const float* means  = (const float*)d_in[0];
  const float* opac   = (const float*)d_in[1];
  const float* scales = (const float*)d_in[2];
  const float* rots   = (const float*)d_in[3];
  const float4* feats = (const float4*)d_in[4];

  char* ws = (char*)d_ws;
  int* tileCnt     = (int*)ws;                        // 6.4 KB
  int* tileIdx     = (int*)(ws + 64 * 1024);          // 800 KB
  float4* tilePack = (float4*)(ws + 1024 * 1024);     // 13.1 MB

  hipMemsetAsync(tileCnt, 0, NTILES * sizeof(int), stream);
  gv_precompute_bin<<<128, 64, 0, stream>>>(means, opac, scales, rots,
                                            tileCnt, tileIdx, tilePack);
  dim3 grid(TTZ, TTY, TTX);
  gv_voxelize<<<grid, 256, 0, stream>>>(feats, tileCnt, tileIdx, tilePack,
                                        (float4*)d_out);
}

// Round 17
// 122.602 us; speedup vs baseline: 1.0764x; 1.0065x over previous
//
#include <hip/hip_runtime.h>

#define HH 160
#define WW 160
#define DD 16
#define NG 8192
#define VOXEL 0.4f

// tiles: 20 x 20 x 4 (each 8x8x4 voxels) = 1600 tiles
#define TTX 20
#define TTY 20
#define TTZ 4
#define NTILES (TTX * TTY * TTZ)
#define CAP 128   // survivors per tile: lambda ~61, P(>128) ~ 8.6 sigma -> safe

// d_ws layout:
//   tileCnt  : NTILES int (6.4 KB)                @ 0
//   tilePack : NTILES * CAP * 4 float4 (13.1 MB)  @ 64 KB
// tilePack record (4 float4 = 64 B), R13 layout:
//   [0] = (mu.x, mu.y, mu.z, opacity)
//   [1] = (3sx,  3sy,  3sz,  as_float(g))   <- gate data, always read
//   [2] = (ci00, ci01, ci02, ci11)          <- read only when __any(pass)
//   [3] = (ci12, ci22, 0, 0)

__global__ __launch_bounds__(64) void gv_precompute_bin(
    const float* __restrict__ means, const float* __restrict__ opac,
    const float* __restrict__ scales, const float* __restrict__ rots,
    int* __restrict__ tileCnt, float4* __restrict__ tilePack) {
  int g = blockIdx.x * 64 + threadIdx.x;
  if (g >= NG) return;
  float qw = rots[g * 4 + 0], qx = rots[g * 4 + 1];
  float qy = rots[g * 4 + 2], qz = rots[g * 4 + 3];
  float inv = rsqrtf(qw * qw + qx * qx + qy * qy + qz * qz);
  qw *= inv; qx *= inv; qy *= inv; qz *= inv;
  float R[3][3];
  R[0][0] = 1.f - 2.f * (qy * qy + qz * qz);
  R[0][1] = 2.f * (qx * qy - qw * qz);
  R[0][2] = 2.f * (qx * qz + qw * qy);
  R[1][0] = 2.f * (qx * qy + qw * qz);
  R[1][1] = 1.f - 2.f * (qx * qx + qz * qz);
  R[1][2] = 2.f * (qy * qz - qw * qx);
  R[2][0] = 2.f * (qx * qz - qw * qy);
  R[2][1] = 2.f * (qy * qz + qw * qx);
  R[2][2] = 1.f - 2.f * (qx * qx + qy * qy);
  float sx = scales[g * 3 + 0], sy = scales[g * 3 + 1], sz = scales[g * 3 + 2];
  float s2[3] = {sx * sx, sy * sy, sz * sz};
  float is2[3] = {1.f / s2[0], 1.f / s2[1], 1.f / s2[2]};
  float cov00 = 0.f, cov11 = 0.f, cov22 = 0.f;
  float ci00 = 0.f, ci01 = 0.f, ci02 = 0.f, ci11 = 0.f, ci12 = 0.f, ci22 = 0.f;
#pragma unroll
  for (int c = 0; c < 3; c++) {
    cov00 += R[0][c] * R[0][c] * s2[c];
    cov11 += R[1][c] * R[1][c] * s2[c];
    cov22 += R[2][c] * R[2][c] * s2[c];
    ci00 += R[0][c] * R[0][c] * is2[c];
    ci01 += R[0][c] * R[1][c] * is2[c];
    ci02 += R[0][c] * R[2][c] * is2[c];
    ci11 += R[1][c] * R[1][c] * is2[c];
    ci12 += R[1][c] * R[2][c] * is2[c];
    ci22 += R[2][c] * R[2][c] * is2[c];
  }
  float mx = means[g * 3 + 0], my = means[g * 3 + 1], mz = means[g * 3 + 2];
  float bx = 3.f * sqrtf(cov00), by = 3.f * sqrtf(cov11), bz = 3.f * sqrtf(cov22);

  const float eps = 1e-4f;
  int i0 = (int)ceilf((mx - bx + 32.f) * 2.5f - 0.5f - eps);
  int i1 = (int)floorf((mx + bx + 32.f) * 2.5f - 0.5f + eps);
  int j0 = (int)ceilf((my - by + 32.f) * 2.5f - 0.5f - eps);
  int j1 = (int)floorf((my + by + 32.f) * 2.5f - 0.5f + eps);
  int k0 = (int)ceilf((mz - bz + 1.f) * 2.5f - 0.5f - eps);
  int k1 = (int)floorf((mz + bz + 1.f) * 2.5f - 0.5f + eps);
  i0 = max(i0, 0); i1 = min(i1, HH - 1);
  j0 = max(j0, 0); j1 = min(j1, WW - 1);
  k0 = max(k0, 0); k1 = min(k1, DD - 1);
  if (i0 > i1 || j0 > j1 || k0 > k1) return;

  float4 p0 = make_float4(mx, my, mz, opac[g]);
  float4 p1 = make_float4(bx, by, bz, __int_as_float(g));
  float4 p2 = make_float4(ci00, ci01, ci02, ci11);
  float4 p3 = make_float4(ci12, ci22, 0.f, 0.f);

  int ti0 = i0 >> 3, ti1 = i1 >> 3;
  int tj0 = j0 >> 3, tj1 = j1 >> 3;
  int tk0 = k0 >> 2, tk1 = k1 >> 2;
  for (int ti = ti0; ti <= ti1; ti++)
    for (int tj = tj0; tj <= tj1; tj++)
      for (int tk = tk0; tk <= tk1; tk++) {
        int t = (ti * TTY + tj) * TTZ + tk;
        int pos = atomicAdd(&tileCnt[t], 1);
        if (pos < CAP) {
          float4* __restrict__ d = tilePack + ((size_t)t * CAP + pos) * 4;
          d[0] = p0;  d[1] = p1;  d[2] = p2;  d[3] = p3;
        }
      }
}

// Voxelize: R13 inner loop, 8 WAVES per block = 4 voxel subsets (4x4x4)
// x 2 list halves (odd/even PAIRS). 512-thread blocks -> 4 blocks/CU
// (thread-limited) = 8 waves/SIMD resident vs R13's measured 2.8 -> the
// exposed ~370cy SMEM/LDS chain per pair is covered by 2.8x more overlap.
// Halves combined by a 2-phase pairwise LDS reduce (18 KB, 3 barriers).
__global__ __launch_bounds__(512) void gv_voxelize(
    const float4* __restrict__ feats, const int* __restrict__ tileCnt,
    const float4* __restrict__ tilePack, float4* __restrict__ out) {
  __shared__ float4 s_pack[CAP * 4];     // 8 KB
  __shared__ float4 s_red[2][64][9];     // 18 KB ([64][9] pad: avoid 32-way)

  int tid = threadIdx.x;
  int wid = tid >> 6, l = tid & 63;
  int sub = wid >> 1;                    // voxel subset 0..3 (4x4x4)
  int h = wid & 1;                       // list half (pairs 2h,2h+1 mod 4)
  int dk = l & 3;
  int dj = (sub & 1) * 4 + ((l >> 2) & 3);
  int di = (sub >> 1) * 4 + (l >> 4);
  int tk = blockIdx.x, tj = blockIdx.y, ti = blockIdx.z;
  int i = ti * 8 + di, j = tj * 8 + dj, k = tk * 4 + dk;

  float px = (i + 0.5f) * VOXEL - 32.f;
  float py = (j + 0.5f) * VOXEL - 32.f;
  float pz = (k + 0.5f) * VOXEL - 1.f;

  int t = (ti * TTY + tj) * TTZ + tk;
  int cnt = tileCnt[t];
  cnt = min(cnt, CAP);

  // stage pack records (coalesced; cnt*4 <= 512 -> one float4 per thread)
  {
    const float4* __restrict__ src = tilePack + (size_t)t * CAP * 4;
    int tot = cnt * 4;
    for (int m = tid; m < tot; m += 512) s_pack[m] = src[m];
  }
  __syncthreads();

  float4 acc[8];
#pragma unroll
  for (int f = 0; f < 8; f++) acc[f] = make_float4(0.f, 0.f, 0.f, 0.f);

  int n = 2 * h;
  for (; n + 2 <= cnt; n += 4) {
    float4 a0 = s_pack[n * 4 + 0], b0 = s_pack[n * 4 + 1];
    float4 a1 = s_pack[n * 4 + 4], b1 = s_pack[n * 4 + 5];

    int g0 = __builtin_amdgcn_readfirstlane(__float_as_int(b0.w));
    int g1 = __builtin_amdgcn_readfirstlane(__float_as_int(b1.w));
    const float4* __restrict__ fp0 = feats + (size_t)g0 * 8;
    const float4* __restrict__ fp1 = feats + (size_t)g1 * 8;
    float4 F0[8], F1[8];
#pragma unroll
    for (int f = 0; f < 8; f++) F0[f] = fp0[f];
#pragma unroll
    for (int f = 0; f < 8; f++) F1[f] = fp1[f];

    float dx0 = px - a0.x, dy0 = py - a0.y, dz0 = pz - a0.z;
    float dx1 = px - a1.x, dy1 = py - a1.y, dz1 = pz - a1.z;
    bool in0 = (fabsf(dx0) <= b0.x) & (fabsf(dy0) <= b0.y) & (fabsf(dz0) <= b0.z);
    bool in1 = (fabsf(dx1) <= b1.x) & (fabsf(dy1) <= b1.y) & (fabsf(dz1) <= b1.z);

    if (__any(in0)) {
      float4 c0 = s_pack[n * 4 + 2], d0 = s_pack[n * 4 + 3];
      float maha = c0.x * dx0 * dx0 + c0.w * dy0 * dy0 + d0.y * dz0 * dz0 +
                   2.f * (c0.y * dx0 * dy0 + c0.z * dx0 * dz0 + d0.x * dy0 * dz0);
      float wgt = in0 ? a0.w * __expf(-0.5f * maha) : 0.f;
#pragma unroll
      for (int f = 0; f < 8; f++) {
        acc[f].x += wgt * F0[f].x;
        acc[f].y += wgt * F0[f].y;
        acc[f].z += wgt * F0[f].z;
        acc[f].w += wgt * F0[f].w;
      }
    }
    if (__any(in1)) {
      float4 c1 = s_pack[n * 4 + 6], d1 = s_pack[n * 4 + 7];
      float maha = c1.x * dx1 * dx1 + c1.w * dy1 * dy1 + d1.y * dz1 * dz1 +
                   2.f * (c1.y * dx1 * dy1 + c1.z * dx1 * dz1 + d1.x * dy1 * dz1);
      float wgt = in1 ? a1.w * __expf(-0.5f * maha) : 0.f;
#pragma unroll
      for (int f = 0; f < 8; f++) {
        acc[f].x += wgt * F1[f].x;
        acc[f].y += wgt * F1[f].y;
        acc[f].z += wgt * F1[f].z;
        acc[f].w += wgt * F1[f].w;
      }
    }
  }
  if (n < cnt) {   // n+2 > cnt -> n == cnt-1: single tail gaussian
    float4 pa = s_pack[n * 4 + 0], pb = s_pack[n * 4 + 1];
    int gg = __builtin_amdgcn_readfirstlane(__float_as_int(pb.w));
    const float4* __restrict__ fp = feats + (size_t)gg * 8;
    float dx = px - pa.x, dy = py - pa.y, dz = pz - pa.z;
    bool in = (fabsf(dx) <= pb.x) & (fabsf(dy) <= pb.y) & (fabsf(dz) <= pb.z);
    if (__any(in)) {
      float4 pc = s_pack[n * 4 + 2], pd = s_pack[n * 4 + 3];
      float maha = pc.x * dx * dx + pc.w * dy * dy + pd.y * dz * dz +
                   2.f * (pc.y * dx * dy + pc.z * dx * dz + pd.x * dy * dz);
      float wgt = in ? pa.w * __expf(-0.5f * maha) : 0.f;
#pragma unroll
      for (int f = 0; f < 8; f++) {
        float4 fv = fp[f];
        acc[f].x += wgt * fv.x;
        acc[f].y += wgt * fv.y;
        acc[f].z += wgt * fv.z;
        acc[f].w += wgt * fv.w;
      }
    }
  }

  // 2-phase pairwise reduce (h=1 publishes, h=0 adds + stores)
  size_t v = ((size_t)i * WW + j) * DD + k;
  float4* o = out + v * 8;

  if (h && sub < 2) {
#pragma unroll
    for (int f = 0; f < 8; f++) s_red[sub][l][f] = acc[f];
  }
  __syncthreads();
  if (!h && sub < 2) {
#pragma unroll
    for (int f = 0; f < 8; f++) {
      float4 r = s_red[sub][l][f];
      o[f] = make_float4(acc[f].x + r.x, acc[f].y + r.y,
                         acc[f].z + r.z, acc[f].w + r.w);
    }
  }
  __syncthreads();
  if (h && sub >= 2) {
#pragma unroll
    for (int f = 0; f < 8; f++) s_red[sub - 2][l][f] = acc[f];
  }
  __syncthreads();
  if (!h && sub >= 2) {
#pragma unroll
    for (int f = 0; f < 8; f++) {
      float4 r = s_red[sub - 2][l][f];
      o[f] = make_float4(acc[f].x + r.x, acc[f].y + r.y,
                         acc[f].z + r.z, acc[f].w + r.w);
    }
  }
}

extern "C" void kernel_launch(void* const* d_in, const int* in_sizes, int n_in,
                              void* d_out, int out_size, void* d_ws, size_t ws_size,
                              hipStream_t stream) {
  const float* means  = (const float*)d_in[0];
  const float* opac   = (const float*)d_in[1];
  const float* scales = (const float*)d_in[2];
  const float* rots   = (const float*)d_in[3];
  const float4* feats = (const float4*)d_in[4];

  char* ws = (char*)d_ws;
  int* tileCnt     = (int*)ws;                        // 6.4 KB
  float4* tilePack = (float4*)(ws + 64 * 1024);       // 13.1 MB

  hipMemsetAsync(tileCnt, 0, NTILES * sizeof(int), stream);
  gv_precompute_bin<<<128, 64, 0, stream>>>(means, opac, scales, rots,
                                            tileCnt, tilePack);
  dim3 grid(TTZ, TTY, TTX);
  gv_voxelize<<<grid, 512, 0, stream>>>(feats, tileCnt, tilePack,
                                        (float4*)d_out);
}

// Round 18
// 122.116 us; speedup vs baseline: 1.0807x; 1.0040x over previous
//
#include <hip/hip_runtime.h>

#define HH 160
#define WW 160
#define DD 16
#define NG 8192
#define VOXEL 0.4f

// tiles: 20 x 20 x 4 (each 8x8x4 voxels) = 1600 tiles
#define TTX 20
#define TTY 20
#define TTZ 4
#define NTILES (TTX * TTY * TTZ)
#define CAP 128   // survivors per tile: lambda ~61, P(>128) ~ 8.6 sigma -> safe

// d_ws layout:
//   tileCnt  : NTILES int (6.4 KB)                @ 0
//   tilePack : NTILES * CAP * 4 float4 (13.1 MB)  @ 64 KB
// tilePack record (4 float4 = 64 B). Layout chosen so the voxelize inner
// loop reads only [0],[1] for the bbox gate (+index for early feats issue);
// [2],[3] are read ONLY when the wave passes the gate:
//   [0] = (mu.x, mu.y, mu.z, opacity)
//   [1] = (3sx,  3sy,  3sz,  as_float(g))
//   [2] = (ci00, ci01, ci02, ci11)
//   [3] = (ci12, ci22, 0, 0)

__global__ __launch_bounds__(64) void gv_precompute_bin(
    const float* __restrict__ means, const float* __restrict__ opac,
    const float* __restrict__ scales, const float* __restrict__ rots,
    int* __restrict__ tileCnt, float4* __restrict__ tilePack) {
  int g = blockIdx.x * 64 + threadIdx.x;
  if (g >= NG) return;
  float qw = rots[g * 4 + 0], qx = rots[g * 4 + 1];
  float qy = rots[g * 4 + 2], qz = rots[g * 4 + 3];
  float inv = rsqrtf(qw * qw + qx * qx + qy * qy + qz * qz);
  qw *= inv; qx *= inv; qy *= inv; qz *= inv;
  float R[3][3];
  R[0][0] = 1.f - 2.f * (qy * qy + qz * qz);
  R[0][1] = 2.f * (qx * qy - qw * qz);
  R[0][2] = 2.f * (qx * qz + qw * qy);
  R[1][0] = 2.f * (qx * qy + qw * qz);
  R[1][1] = 1.f - 2.f * (qx * qx + qz * qz);
  R[1][2] = 2.f * (qy * qz - qw * qx);
  R[2][0] = 2.f * (qx * qz - qw * qy);
  R[2][1] = 2.f * (qy * qz + qw * qx);
  R[2][2] = 1.f - 2.f * (qx * qx + qy * qy);
  float sx = scales[g * 3 + 0], sy = scales[g * 3 + 1], sz = scales[g * 3 + 2];
  float s2[3] = {sx * sx, sy * sy, sz * sz};
  float is2[3] = {1.f / s2[0], 1.f / s2[1], 1.f / s2[2]};
  float cov00 = 0.f, cov11 = 0.f, cov22 = 0.f;
  float ci00 = 0.f, ci01 = 0.f, ci02 = 0.f, ci11 = 0.f, ci12 = 0.f, ci22 = 0.f;
#pragma unroll
  for (int c = 0; c < 3; c++) {
    cov00 += R[0][c] * R[0][c] * s2[c];
    cov11 += R[1][c] * R[1][c] * s2[c];
    cov22 += R[2][c] * R[2][c] * s2[c];
    ci00 += R[0][c] * R[0][c] * is2[c];
    ci01 += R[0][c] * R[1][c] * is2[c];
    ci02 += R[0][c] * R[2][c] * is2[c];
    ci11 += R[1][c] * R[1][c] * is2[c];
    ci12 += R[1][c] * R[2][c] * is2[c];
    ci22 += R[2][c] * R[2][c] * is2[c];
  }
  float mx = means[g * 3 + 0], my = means[g * 3 + 1], mz = means[g * 3 + 2];
  float bx = 3.f * sqrtf(cov00), by = 3.f * sqrtf(cov11), bz = 3.f * sqrtf(cov22);

  // voxel-center index ranges covered by bbox (with float-slop margin)
  const float eps = 1e-4f;
  int i0 = (int)ceilf((mx - bx + 32.f) * 2.5f - 0.5f - eps);
  int i1 = (int)floorf((mx + bx + 32.f) * 2.5f - 0.5f + eps);
  int j0 = (int)ceilf((my - by + 32.f) * 2.5f - 0.5f - eps);
  int j1 = (int)floorf((my + by + 32.f) * 2.5f - 0.5f + eps);
  int k0 = (int)ceilf((mz - bz + 1.f) * 2.5f - 0.5f - eps);
  int k1 = (int)floorf((mz + bz + 1.f) * 2.5f - 0.5f + eps);
  i0 = max(i0, 0); i1 = min(i1, HH - 1);
  j0 = max(j0, 0); j1 = min(j1, WW - 1);
  k0 = max(k0, 0); k1 = min(k1, DD - 1);
  if (i0 > i1 || j0 > j1 || k0 > k1) return;

  float4 p0 = make_float4(mx, my, mz, opac[g]);
  float4 p1 = make_float4(bx, by, bz, __int_as_float(g));
  float4 p2 = make_float4(ci00, ci01, ci02, ci11);
  float4 p3 = make_float4(ci12, ci22, 0.f, 0.f);

  int ti0 = i0 >> 3, ti1 = i1 >> 3;
  int tj0 = j0 >> 3, tj1 = j1 >> 3;
  int tk0 = k0 >> 2, tk1 = k1 >> 2;
  for (int ti = ti0; ti <= ti1; ti++)
    for (int tj = tj0; tj <= tj1; tj++)
      for (int tk = tk0; tk <= tk1; tk++) {
        int t = (ti * TTY + tj) * TTZ + tk;
        int pos = atomicAdd(&tileCnt[t], 1);
        if (pos < CAP) {
          float4* __restrict__ d = tilePack + ((size_t)t * CAP + pos) * 4;
          d[0] = p0;  d[1] = p1;  d[2] = p2;  d[3] = p3;
        }
      }
}

// Voxelize (measured best, R13): LDS pack broadcast + L2-hot feats s_load,
// 2-wide pairing, 4 waves/block; ci reads gated behind __any(in) so the
// fail path costs 2 ds_reads instead of 4. Feats s_loads issue early
// (index rides in [1].w) and overlap the gate ds_read.
__global__ __launch_bounds__(256) void gv_voxelize(
    const float4* __restrict__ feats, const int* __restrict__ tileCnt,
    const float4* __restrict__ tilePack, float4* __restrict__ out) {
  __shared__ float4 s_pack[CAP * 4];   // 8 KB

  int tid = threadIdx.x;
  int dk = tid & 3, dj = (tid >> 2) & 7, di = tid >> 5;
  int tk = blockIdx.x, tj = blockIdx.y, ti = blockIdx.z;
  int i = ti * 8 + di, j = tj * 8 + dj, k = tk * 4 + dk;

  float px = (i + 0.5f) * VOXEL - 32.f;
  float py = (j + 0.5f) * VOXEL - 32.f;
  float pz = (k + 0.5f) * VOXEL - 1.f;

  int t = (ti * TTY + tj) * TTZ + tk;
  int cnt = tileCnt[t];
  cnt = min(cnt, CAP);

  // stage pack records (coalesced, parallel)
  {
    const float4* __restrict__ src = tilePack + (size_t)t * CAP * 4;
    int tot = cnt * 4;
    for (int m = tid; m < tot; m += 256) s_pack[m] = src[m];
  }
  __syncthreads();

  float4 acc[8];
#pragma unroll
  for (int f = 0; f < 8; f++) acc[f] = make_float4(0.f, 0.f, 0.f, 0.f);

  int n = 0;
  for (; n + 2 <= cnt; n += 2) {
    float4 a0 = s_pack[n * 4 + 0], b0 = s_pack[n * 4 + 1];
    float4 a1 = s_pack[n * 4 + 4], b1 = s_pack[n * 4 + 5];

    int g0 = __builtin_amdgcn_readfirstlane(__float_as_int(b0.w));
    int g1 = __builtin_amdgcn_readfirstlane(__float_as_int(b1.w));
    const float4* __restrict__ fp0 = feats + (size_t)g0 * 8;
    const float4* __restrict__ fp1 = feats + (size_t)g1 * 8;
    // issue both feats load sets early (uniform -> s_load_dwordx16 pairs)
    float4 F0[8], F1[8];
#pragma unroll
    for (int f = 0; f < 8; f++) F0[f] = fp0[f];
#pragma unroll
    for (int f = 0; f < 8; f++) F1[f] = fp1[f];

    float dx0 = px - a0.x, dy0 = py - a0.y, dz0 = pz - a0.z;
    float dx1 = px - a1.x, dy1 = py - a1.y, dz1 = pz - a1.z;
    bool in0 = (fabsf(dx0) <= b0.x) & (fabsf(dy0) <= b0.y) & (fabsf(dz0) <= b0.z);
    bool in1 = (fabsf(dx1) <= b1.x) & (fabsf(dy1) <= b1.y) & (fabsf(dz1) <= b1.z);

    if (__any(in0)) {
      float4 c0 = s_pack[n * 4 + 2], d0 = s_pack[n * 4 + 3];
      float maha = c0.x * dx0 * dx0 + c0.w * dy0 * dy0 + d0.y * dz0 * dz0 +
                   2.f * (c0.y * dx0 * dy0 + c0.z * dx0 * dz0 + d0.x * dy0 * dz0);
      float wgt = in0 ? a0.w * __expf(-0.5f * maha) : 0.f;
#pragma unroll
      for (int f = 0; f < 8; f++) {
        acc[f].x += wgt * F0[f].x;
        acc[f].y += wgt * F0[f].y;
        acc[f].z += wgt * F0[f].z;
        acc[f].w += wgt * F0[f].w;
      }
    }
    if (__any(in1)) {
      float4 c1 = s_pack[n * 4 + 6], d1 = s_pack[n * 4 + 7];
      float maha = c1.x * dx1 * dx1 + c1.w * dy1 * dy1 + d1.y * dz1 * dz1 +
                   2.f * (c1.y * dx1 * dy1 + c1.z * dx1 * dz1 + d1.x * dy1 * dz1);
      float wgt = in1 ? a1.w * __expf(-0.5f * maha) : 0.f;
#pragma unroll
      for (int f = 0; f < 8; f++) {
        acc[f].x += wgt * F1[f].x;
        acc[f].y += wgt * F1[f].y;
        acc[f].z += wgt * F1[f].z;
        acc[f].w += wgt * F1[f].w;
      }
    }
  }
  if (n < cnt) {
    float4 pa = s_pack[n * 4 + 0], pb = s_pack[n * 4 + 1];
    int gg = __builtin_amdgcn_readfirstlane(__float_as_int(pb.w));
    const float4* __restrict__ fp = feats + (size_t)gg * 8;
    float dx = px - pa.x, dy = py - pa.y, dz = pz - pa.z;
    bool in = (fabsf(dx) <= pb.x) & (fabsf(dy) <= pb.y) & (fabsf(dz) <= pb.z);
    if (__any(in)) {
      float4 pc = s_pack[n * 4 + 2], pd = s_pack[n * 4 + 3];
      float maha = pc.x * dx * dx + pc.w * dy * dy + pd.y * dz * dz +
                   2.f * (pc.y * dx * dy + pc.z * dx * dz + pd.x * dy * dz);
      float wgt = in ? pa.w * __expf(-0.5f * maha) : 0.f;
#pragma unroll
      for (int f = 0; f < 8; f++) {
        float4 fv = fp[f];
        acc[f].x += wgt * fv.x;
        acc[f].y += wgt * fv.y;
        acc[f].z += wgt * fv.z;
        acc[f].w += wgt * fv.w;
      }
    }
  }

  size_t v = ((size_t)i * WW + j) * DD + k;
  float4* o = out + v * 8;
#pragma unroll
  for (int f = 0; f < 8; f++) o[f] = acc[f];
}

extern "C" void kernel_launch(void* const* d_in, const int* in_sizes, int n_in,
                              void* d_out, int out_size, void* d_ws, size_t ws_size,
                              hipStream_t stream) {
  const float* means  = (const float*)d_in[0];
  const float* opac   = (const float*)d_in[1];
  const float* scales = (const float*)d_in[2];
  const float* rots   = (const float*)d_in[3];
  const float4* feats = (const float4*)d_in[4];

  char* ws = (char*)d_ws;
  int* tileCnt     = (int*)ws;                        // 6.4 KB
  float4* tilePack = (float4*)(ws + 64 * 1024);       // 13.1 MB

  hipMemsetAsync(tileCnt, 0, NTILES * sizeof(int), stream);
  gv_precompute_bin<<<128, 64, 0, stream>>>(means, opac, scales, rots,
                                            tileCnt, tilePack);
  dim3 grid(TTZ, TTY, TTX);
  gv_voxelize<<<grid, 256, 0, stream>>>(feats, tileCnt, tilePack,
                                        (float4*)d_out);
}